// Round 12
// baseline (137.921 us; speedup 1.0000x reference)
//
#include <hip/hip_runtime.h>
#include <hip/hip_bf16.h>
#include <math.h>

// Shapes
#define QL 32768
#define DD 1024
#define NTOK 64

using short8   = __attribute__((ext_vector_type(8))) short;
using f32x4    = __attribute__((ext_vector_type(4))) float;
using float4v  = __attribute__((ext_vector_type(4))) float;
using ushort4v = __attribute__((ext_vector_type(4))) unsigned short;

// RNE f32->bf16 via bit trick (exact RNE)
__device__ __forceinline__ unsigned short f2bf(float f) {
    unsigned int u = __float_as_uint(f);
    unsigned int r = (u + 0x7FFFu + ((u >> 16) & 1u)) >> 16;
    return (unsigned short)r;
}

// async global->LDS, 16B per lane; dest = wave-uniform base + lane*16
__device__ __forceinline__ void gload_lds16(const void* g, void* l) {
    __builtin_amdgcn_global_load_lds(
        (const __attribute__((address_space(1))) void*)g,
        (__attribute__((address_space(3))) void*)l,
        16, 0, 0);
}

// ---------------------------------------------------------------------------
// Prologue 1: transpose-convert Wq -> WqT bf16, Pv -> PvT bf16.
// ---------------------------------------------------------------------------
__global__ __launch_bounds__(256) void prep_transpose_kernel(
        const float* __restrict__ Wq, const float* __restrict__ Pv,
        unsigned short* __restrict__ WqT, unsigned short* __restrict__ PvT) {
    __shared__ float tile[64][65];
    int b = blockIdx.x;
    const float* src; unsigned short* dst; int R, C, r0, c0;
    if (b < 256) { src = Wq; dst = WqT; R = 1024; C = 1024;
                   r0 = (b >> 4) << 6; c0 = (b & 15) << 6; }
    else         { b -= 256; src = Pv; dst = PvT; R = 64; C = 1024;
                   r0 = 0; c0 = b << 6; }
    const int tid = threadIdx.x;
#pragma unroll
    for (int i = 0; i < 16; ++i) {
        const int lin = tid + 256 * i;
        const int row = lin >> 6, col = lin & 63;
        if (r0 + row < R)
            tile[row][col] = src[(size_t)(r0 + row) * C + c0 + col];
    }
    __syncthreads();
#pragma unroll
    for (int i = 0; i < 16; ++i) {
        const int lin = tid + 256 * i;
        const int row = lin >> 6, col = lin & 63;
        if (r0 + col < R)
            dst[(size_t)(c0 + row) * R + r0 + col] = f2bf(tile[col][row]);
    }
}

// ---------------------------------------------------------------------------
// Prologue 2: Kp = Pk @ Wq via bf16 MFMA (B from WqT). grid 16 x 256.
// ---------------------------------------------------------------------------
__global__ __launch_bounds__(256) void kp_mfma_kernel(
        const float* __restrict__ Pk, const unsigned short* __restrict__ WqT,
        unsigned short* __restrict__ Kp) {
    const int tid = threadIdx.x;
    const int w   = tid >> 6;
    const int l   = tid & 63;
    const int lhi = l >> 4;
    const int llo = l & 15;
    const int N0  = blockIdx.x * 64;

    f32x4 acc[4];
#pragma unroll
    for (int ct = 0; ct < 4; ++ct) acc[ct] = (f32x4){0.f, 0.f, 0.f, 0.f};

    for (int kb = 0; kb < 32; ++kb) {
        const int k0 = kb * 32 + lhi * 8;
        float4v p0 = *(const float4v*)(Pk + (size_t)(w * 16 + llo) * DD + k0);
        float4v p1 = *(const float4v*)(Pk + (size_t)(w * 16 + llo) * DD + k0 + 4);
        short8 a;
        a[0] = (short)f2bf(p0.x); a[1] = (short)f2bf(p0.y);
        a[2] = (short)f2bf(p0.z); a[3] = (short)f2bf(p0.w);
        a[4] = (short)f2bf(p1.x); a[5] = (short)f2bf(p1.y);
        a[6] = (short)f2bf(p1.z); a[7] = (short)f2bf(p1.w);
#pragma unroll
        for (int ct = 0; ct < 4; ++ct) {
            short8 b = *(const short8*)(WqT + (size_t)(N0 + ct * 16 + llo) * DD + k0);
            acc[ct] = __builtin_amdgcn_mfma_f32_16x16x32_bf16(a, b, acc[ct], 0, 0, 0);
        }
    }
#pragma unroll
    for (int ct = 0; ct < 4; ++ct) {
#pragma unroll
        for (int j = 0; j < 4; ++j) {
            const int t = w * 16 + lhi * 4 + j;
            const int d = N0 + ct * 16 + llo;
            Kp[(size_t)t * DD + d] = f2bf(acc[ct][j]);
        }
    }
}

// ---------------------------------------------------------------------------
// Fused main: 512 blocks x 512 thr (8 waves), 64 q-rows/block.
// LDS = 72 KB -> 2 blocks/CU (16 waves/CU): co-resident blocks stagger
// phases, overlapping the A read-stream with the C write-stream chip-wide.
// Phase A: 16 K-steps of 64. 3-deep circular bufs, global_load_lds for
//   A (x fp32 [64][64], 16 KB/step) and B (Kp bf16 [64][64], 8 KB/step);
//   counted s_waitcnt vmcnt(3) (= 3 vm-ops/thread/step) + raw s_barrier.
//   Wave (wr,wt): rows wr*32..+32 (2 frags), tokens wt*16..+16. Rule #21
//   swizzles as r10 (verified): A 32B-granule XOR (row&7), B 16B-chunk XOR.
// Phase B: partials -> sSf[64][68] f32 (alias A-bufs 0/1) -> 8-lane shfl
//   norm*8 -> exact GELU -> s' bf16 [64][128B] swizzled in sP (alias A-buf 2).
// Phase C: y = s' @ Pv swapped MFMA (D[m=d][n=q]); PvT frags (64 VGPR) +
//   s' frags loaded at entry; float4 stores. Wave w owns d-cols w*128..+128.
// ---------------------------------------------------------------------------
__global__ __launch_bounds__(512) void pattn_kernel(
        const float* __restrict__ x, const unsigned short* __restrict__ Kp,
        const unsigned short* __restrict__ PvT, float* __restrict__ out) {
    __shared__ __align__(16) unsigned char smem[73728];
    unsigned char* Ab = smem;            // 3 x 16384: x fp32 [64][256B]
    unsigned char* Bb = smem + 49152;    // 3 x 8192:  Kp bf16 [64][128B]

    const int tid = threadIdx.x;
    const int w   = tid >> 6;     // 0..7
    const int l   = tid & 63;
    const int lhi = l >> 4;       // 0..3
    const int llo = l & 15;       // 0..15
    const int wr  = w >> 2;       // 0..1  row-half
    const int wt  = w & 3;        // 0..3  token-slice
    const int R0  = blockIdx.x * 64;
    const char* xb  = (const char*)x;
    const char* kpb = (const char*)Kp;

    f32x4 acc[2];
    acc[0] = (f32x4){0.f, 0.f, 0.f, 0.f};
    acc[1] = (f32x4){0.f, 0.f, 0.f, 0.f};

    // stage K-step t: 2 A-gloads + 1 B-gload per thread (3 vm ops/step).
    // A [64 rows][16 chunks16]: LDS chunk c <- global chunk c ^ ((row&7)<<1).
    // B [64 rows][8 chunks16]:  LDS chunk c <- global chunk c ^ (row&7).
#define STAGE(t)                                                                \
    {                                                                           \
        unsigned char* abuf = Ab + ((t) % 3) * 16384;                           \
        unsigned char* bbuf = Bb + ((t) % 3) * 8192;                            \
        _Pragma("unroll")                                                       \
        for (int i = 0; i < 2; ++i) {                                           \
            const int row = i * 32 + w * 4 + (l >> 4);                          \
            const int csw = (l & 15) ^ ((row & 7) << 1);                        \
            gload_lds16(xb + (size_t)(R0 + row) * 4096 + (t) * 256 + csw * 16,  \
                        (void*)(abuf + (i * 32 + w * 4) * 256));                \
        }                                                                       \
        const int brow = w * 8 + (l >> 3);                                      \
        const int bcs  = (l & 7) ^ (brow & 7);                                  \
        gload_lds16(kpb + (size_t)brow * 2048 + (t) * 128 + bcs * 16,           \
                    (void*)(bbuf + (w * 8) * 128));                             \
    }

    // compute K-step t: wave (wr,wt): 2 k-subs x 2 row-frags = 4 MFMA.
#define COMPUTE(t)                                                              \
    {                                                                           \
        unsigned char* abuf = Ab + ((t) % 3) * 16384;                           \
        unsigned char* bbuf = Bb + ((t) % 3) * 8192;                            \
        _Pragma("unroll")                                                       \
        for (int ks = 0; ks < 2; ++ks) {                                        \
            const int btok = wt * 16 + llo;                                     \
            const short8 bfrg = *(const short8*)(bbuf + btok * 128 +            \
                                  (((ks * 4 + lhi) ^ (btok & 7)) << 4));        \
            _Pragma("unroll")                                                   \
            for (int rf = 0; rf < 2; ++rf) {                                    \
                const int arow  = wr * 32 + rf * 16 + llo;                      \
                const int abyte = arow * 256 +                                  \
                                  (((ks * 4 + lhi) ^ (arow & 7)) << 5);         \
                const float4v f0 = *(const float4v*)(abuf + abyte);             \
                const float4v f1 = *(const float4v*)(abuf + abyte + 16);        \
                short8 a;                                                       \
                ((__hip_bfloat162*)&a)[0] = __float22bfloat162_rn(float2{f0.x, f0.y}); \
                ((__hip_bfloat162*)&a)[1] = __float22bfloat162_rn(float2{f0.z, f0.w}); \
                ((__hip_bfloat162*)&a)[2] = __float22bfloat162_rn(float2{f1.x, f1.y}); \
                ((__hip_bfloat162*)&a)[3] = __float22bfloat162_rn(float2{f1.z, f1.w}); \
                acc[rf] = __builtin_amdgcn_mfma_f32_16x16x32_bf16(a, bfrg, acc[rf], 0, 0, 0); \
            }                                                                   \
        }                                                                       \
    }

    // ---- Phase A: depth-3 pipeline, counted vmcnt (retire step t, keep t+1) ----
    STAGE(0); STAGE(1);
#pragma unroll
    for (int t = 0; t < 16; ++t) {
        if (t < 15) { asm volatile("s_waitcnt vmcnt(3)" ::: "memory"); }
        else        { asm volatile("s_waitcnt vmcnt(0)" ::: "memory"); }
        __builtin_amdgcn_s_barrier();
        __builtin_amdgcn_sched_barrier(0);
        if (t < 14) STAGE(t + 2);
        COMPUTE(t);
    }
#undef STAGE
#undef COMPUTE

    __syncthreads();   // pipeline retired -> A-bufs free for aliases

    // ---- Phase B: partials -> sSf (A-bufs 0/1), 8-lane norm, GELU -> sP ----
    float (*sSf)[68] = (float (*)[68])(void*)smem;          // [64][68] f32, 17.4 KB
#pragma unroll
    for (int rf = 0; rf < 2; ++rf)
#pragma unroll
        for (int j = 0; j < 4; ++j)
            sSf[wr * 32 + rf * 16 + lhi * 4 + j][wt * 16 + llo] = acc[rf][j];
    __syncthreads();

    unsigned char* sP = smem + 32768;                       // s' [64][128B] swz (A-buf 2)
    {
        const int r  = tid >> 3;          // 0..63 q-row
        const int tq = tid & 7;           // 8-token chunk
        const f32x4 v0 = *(const f32x4*)&sSf[r][tq * 8];
        const f32x4 v1 = *(const f32x4*)&sSf[r][tq * 8 + 4];
        float ssq = v0.x*v0.x + v0.y*v0.y + v0.z*v0.z + v0.w*v0.w
                  + v1.x*v1.x + v1.y*v1.y + v1.z*v1.z + v1.w*v1.w;
        ssq += __shfl_xor(ssq, 1);
        ssq += __shfl_xor(ssq, 2);
        ssq += __shfl_xor(ssq, 4);
        const float scale = 8.0f / sqrtf(ssq);
        short8 gq;
#pragma unroll
        for (int k = 0; k < 4; ++k) {
            const float a0 = v0[k] * scale;
            const float a1 = v1[k] * scale;
            gq[k]     = (short)f2bf(0.5f * a0 * (1.0f + erff(a0 * 0.70710678118654752f)));
            gq[4 + k] = (short)f2bf(0.5f * a1 * (1.0f + erff(a1 * 0.70710678118654752f)));
        }
        *(short8*)(sP + r * 128 + ((tq ^ (r & 7)) << 4)) = gq;
    }
    __syncthreads();

    // ---- Phase C: y = s' @ Pv (swapped: D[m=d][n=q]); float4 stores ----
    const int d0 = w * 128;
    short8 pa0[8], pa1[8];
#pragma unroll
    for (int dt = 0; dt < 8; ++dt) {
        const unsigned short* ap = PvT + (size_t)(d0 + dt * 16 + llo) * 64 + lhi * 8;
        pa0[dt] = *(const short8*)ap;
        pa1[dt] = *(const short8*)(ap + 32);
    }
    short8 sfr[4][2];
#pragma unroll
    for (int qb = 0; qb < 4; ++qb) {
        const int q = qb * 16 + llo;
        sfr[qb][0] = *(const short8*)(sP + q * 128 + (((lhi)     ^ (q & 7)) << 4));
        sfr[qb][1] = *(const short8*)(sP + q * 128 + (((4 + lhi) ^ (q & 7)) << 4));
    }
#pragma unroll 2
    for (int dt = 0; dt < 8; ++dt) {
#pragma unroll
        for (int qb = 0; qb < 4; ++qb) {
            f32x4 cy = (f32x4){0.f, 0.f, 0.f, 0.f};
            cy = __builtin_amdgcn_mfma_f32_16x16x32_bf16(pa0[dt], sfr[qb][0], cy, 0, 0, 0);
            cy = __builtin_amdgcn_mfma_f32_16x16x32_bf16(pa1[dt], sfr[qb][1], cy, 0, 0, 0);
            *(float4v*)(out + (size_t)(R0 + qb * 16 + llo) * DD
                            + d0 + dt * 16 + lhi * 4) = cy;
        }
    }
}

// ---------------------------------------------------------------------------
extern "C" void kernel_launch(void* const* d_in, const int* in_sizes, int n_in,
                              void* d_out, int out_size, void* d_ws, size_t ws_size,
                              hipStream_t stream) {
    (void)in_sizes; (void)n_in; (void)out_size; (void)ws_size;
    const float* x  = (const float*)d_in[0];
    const float* Wq = (const float*)d_in[1];
    const float* Pk = (const float*)d_in[2];
    const float* Pv = (const float*)d_in[3];
    float* out = (float*)d_out;

    // ws layout (2.25 MB total):
    //   WqT bf16 [1024][1024] @ 0            (2 MB)
    //   Kp  bf16 [64][1024]   @ 2 MB         (128 KB)
    //   PvT bf16 [1024][64]   @ 2 MB + 128K  (128 KB)
    unsigned short* WqT = (unsigned short*)d_ws;
    unsigned short* Kp  = (unsigned short*)((char*)d_ws + 2097152);
    unsigned short* PvT = (unsigned short*)((char*)d_ws + 2097152 + 131072);

    prep_transpose_kernel<<<272, 256, 0, stream>>>(Wq, Pv, WqT, PvT);
    kp_mfma_kernel<<<16, 256, 0, stream>>>(Pk, WqT, Kp);
    pattn_kernel<<<512, 512, 0, stream>>>(x, Kp, PvT, out);
}

// Round 13
// 90.827 us; speedup vs baseline: 1.5185x; 1.5185x over previous
//
#include <hip/hip_runtime.h>
#include <hip/hip_bf16.h>
#include <math.h>

// Shapes
#define QL 32768
#define DD 1024
#define NTOK 64

using short8   = __attribute__((ext_vector_type(8))) short;
using f32x4    = __attribute__((ext_vector_type(4))) float;
using float4v  = __attribute__((ext_vector_type(4))) float;
using ushort4v = __attribute__((ext_vector_type(4))) unsigned short;
using ushort8v = __attribute__((ext_vector_type(8))) unsigned short;

// RNE f32->bf16 via bit trick (exact RNE)
__device__ __forceinline__ unsigned short f2bf(float f) {
    unsigned int u = __float_as_uint(f);
    unsigned int r = (u + 0x7FFFu + ((u >> 16) & 1u)) >> 16;
    return (unsigned short)r;
}

// async global->LDS, 16B per lane; dest = wave-uniform base + lane*16
__device__ __forceinline__ void gload_lds16(const void* g, void* l) {
    __builtin_amdgcn_global_load_lds(
        (const __attribute__((address_space(1))) void*)g,
        (__attribute__((address_space(3))) void*)l,
        16, 0, 0);
}

// ---------------------------------------------------------------------------
// Prologue 1: transpose-convert Wq -> WqT bf16, Pv -> PvT bf16.
// ---------------------------------------------------------------------------
__global__ __launch_bounds__(256) void prep_transpose_kernel(
        const float* __restrict__ Wq, const float* __restrict__ Pv,
        unsigned short* __restrict__ WqT, unsigned short* __restrict__ PvT) {
    __shared__ float tile[64][65];
    int b = blockIdx.x;
    const float* src; unsigned short* dst; int R, C, r0, c0;
    if (b < 256) { src = Wq; dst = WqT; R = 1024; C = 1024;
                   r0 = (b >> 4) << 6; c0 = (b & 15) << 6; }
    else         { b -= 256; src = Pv; dst = PvT; R = 64; C = 1024;
                   r0 = 0; c0 = b << 6; }
    const int tid = threadIdx.x;
#pragma unroll
    for (int i = 0; i < 16; ++i) {
        const int lin = tid + 256 * i;
        const int row = lin >> 6, col = lin & 63;
        if (r0 + row < R)
            tile[row][col] = src[(size_t)(r0 + row) * C + c0 + col];
    }
    __syncthreads();
#pragma unroll
    for (int i = 0; i < 16; ++i) {
        const int lin = tid + 256 * i;
        const int row = lin >> 6, col = lin & 63;
        if (r0 + col < R)
            dst[(size_t)(c0 + row) * R + r0 + col] = f2bf(tile[col][row]);
    }
}

// ---------------------------------------------------------------------------
// Prologue 2: Kp = Pk @ Wq via bf16 MFMA (B from WqT). grid 64 x 256:
// block b owns d-cols b*16..b*16+16 (widened from 16 blocks for parallelism).
// ---------------------------------------------------------------------------
__global__ __launch_bounds__(256) void kp_mfma_kernel(
        const float* __restrict__ Pk, const unsigned short* __restrict__ WqT,
        unsigned short* __restrict__ Kp) {
    const int tid = threadIdx.x;
    const int w   = tid >> 6;
    const int l   = tid & 63;
    const int lhi = l >> 4;
    const int llo = l & 15;
    const int N0  = blockIdx.x * 16;

    f32x4 acc = (f32x4){0.f, 0.f, 0.f, 0.f};

    for (int kb = 0; kb < 32; ++kb) {
        const int k0 = kb * 32 + lhi * 8;
        float4v p0 = *(const float4v*)(Pk + (size_t)(w * 16 + llo) * DD + k0);
        float4v p1 = *(const float4v*)(Pk + (size_t)(w * 16 + llo) * DD + k0 + 4);
        short8 a;
        a[0] = (short)f2bf(p0.x); a[1] = (short)f2bf(p0.y);
        a[2] = (short)f2bf(p0.z); a[3] = (short)f2bf(p0.w);
        a[4] = (short)f2bf(p1.x); a[5] = (short)f2bf(p1.y);
        a[6] = (short)f2bf(p1.z); a[7] = (short)f2bf(p1.w);
        short8 b = *(const short8*)(WqT + (size_t)(N0 + llo) * DD + k0);
        acc = __builtin_amdgcn_mfma_f32_16x16x32_bf16(a, b, acc, 0, 0, 0);
    }
#pragma unroll
    for (int j = 0; j < 4; ++j) {
        const int t = w * 16 + lhi * 4 + j;
        Kp[(size_t)t * DD + N0 + llo] = f2bf(acc[j]);
    }
}

// ---------------------------------------------------------------------------
// GEMM1 (r10 phases A+B verbatim): s' = gelu(l2norm_scale(x @ Kp^T)) -> sp.
// grid 256 x 512 (8 waves), 128 q-rows/block. 16 K-steps of 64, 3-deep
// circular gload_lds pipeline (A 32 KB + B 8 KB per step), counted vmcnt(5).
// Epilogue: cross-wave reduce (alias A-bufs) -> norm*8 -> exact GELU ->
// coalesced s' stores to global (4 MB total).
// ---------------------------------------------------------------------------
__global__ __launch_bounds__(512) void gemm1_kernel(
        const float* __restrict__ x, const unsigned short* __restrict__ Kp,
        unsigned short* __restrict__ sp) {
    __shared__ __align__(16) unsigned char smem[122880];   // 3*32K (A) + 3*8K (B)

    const int tid = threadIdx.x;
    const int w   = tid >> 6;     // 0..7
    const int l   = tid & 63;
    const int lhi = l >> 4;       // 0..3
    const int llo = l & 15;       // 0..15
    const int wr  = w >> 2;       // 0..1  row-half
    const int wt  = w & 3;        // 0..3  token-slice
    const int R0  = blockIdx.x * 128;
    const char* xb  = (const char*)x;
    const char* kpb = (const char*)Kp;

    f32x4 acc[4];
#pragma unroll
    for (int rf = 0; rf < 4; ++rf) acc[rf] = (f32x4){0.f, 0.f, 0.f, 0.f};

#define ABUF(t) (smem + ((t) % 3) * 32768)
#define BBUF(t) (smem + 98304 + ((t) % 3) * 8192)

#define STAGE(t)                                                                \
    {                                                                           \
        unsigned char* abuf = ABUF(t);                                          \
        unsigned char* bbuf = BBUF(t);                                          \
        _Pragma("unroll")                                                       \
        for (int i = 0; i < 4; ++i) {                                           \
            const int row = i * 32 + w * 4 + (l >> 4);                          \
            const int csw = (l & 15) ^ ((row & 7) << 1);                        \
            gload_lds16(xb + (size_t)(R0 + row) * 4096 + (t) * 256 + csw * 16,  \
                        (void*)(abuf + (i * 32 + w * 4) * 256));                \
        }                                                                       \
        const int brow = w * 8 + (l >> 3);                                      \
        const int bcs  = (l & 7) ^ (brow & 7);                                  \
        gload_lds16(kpb + (size_t)brow * 2048 + (t) * 128 + bcs * 16,           \
                    (void*)(bbuf + (w * 8) * 128));                             \
    }

#define COMPUTE(t)                                                              \
    {                                                                           \
        unsigned char* abuf = ABUF(t);                                          \
        unsigned char* bbuf = BBUF(t);                                          \
        _Pragma("unroll")                                                       \
        for (int ks = 0; ks < 2; ++ks) {                                        \
            const int btok = wt * 16 + llo;                                     \
            const short8 bfrg = *(const short8*)(bbuf + btok * 128 +            \
                                  (((ks * 4 + lhi) ^ (btok & 7)) << 4));        \
            _Pragma("unroll")                                                   \
            for (int rf = 0; rf < 4; ++rf) {                                    \
                const int arow  = wr * 64 + rf * 16 + llo;                      \
                const int abyte = arow * 256 +                                  \
                                  (((ks * 4 + lhi) ^ (arow & 7)) << 5);         \
                const float4v f0 = *(const float4v*)(abuf + abyte);             \
                const float4v f1 = *(const float4v*)(abuf + abyte + 16);        \
                short8 a;                                                       \
                ((__hip_bfloat162*)&a)[0] = __float22bfloat162_rn(float2{f0.x, f0.y}); \
                ((__hip_bfloat162*)&a)[1] = __float22bfloat162_rn(float2{f0.z, f0.w}); \
                ((__hip_bfloat162*)&a)[2] = __float22bfloat162_rn(float2{f1.x, f1.y}); \
                ((__hip_bfloat162*)&a)[3] = __float22bfloat162_rn(float2{f1.z, f1.w}); \
                acc[rf] = __builtin_amdgcn_mfma_f32_16x16x32_bf16(a, bfrg, acc[rf], 0, 0, 0); \
            }                                                                   \
        }                                                                       \
    }

    // ---- Phase A: depth-3 pipeline, 2-step lookahead, counted vmcnt ----
    STAGE(0); STAGE(1);
#pragma unroll
    for (int t = 0; t < 16; ++t) {
        if (t < 15) { asm volatile("s_waitcnt vmcnt(5)" ::: "memory"); }
        else        { asm volatile("s_waitcnt vmcnt(0)" ::: "memory"); }
        __builtin_amdgcn_s_barrier();
        __builtin_amdgcn_sched_barrier(0);
        if (t < 14) STAGE(t + 2);
        COMPUTE(t);
    }
#undef STAGE
#undef COMPUTE
#undef ABUF
#undef BBUF

    __syncthreads();   // pipeline fully retired -> LDS free for aliases

    // ---- Phase B: partials -> sSf, 4-lane norm, exact GELU -> sp (global) ----
    float (*sSf)[68] = (float (*)[68])(void*)smem;          // [128][68] f32, 34.8 KB
#pragma unroll
    for (int rf = 0; rf < 4; ++rf)
#pragma unroll
        for (int j = 0; j < 4; ++j)
            sSf[wr * 64 + rf * 16 + lhi * 4 + j][wt * 16 + llo] = acc[rf][j];
    __syncthreads();

    {
        const int r  = tid >> 2;          // 0..127 q-row
        const int tq = tid & 3;           // 16-token slice
        const f32x4 v0 = *(const f32x4*)&sSf[r][tq * 16];
        const f32x4 v1 = *(const f32x4*)&sSf[r][tq * 16 + 4];
        const f32x4 v2 = *(const f32x4*)&sSf[r][tq * 16 + 8];
        const f32x4 v3 = *(const f32x4*)&sSf[r][tq * 16 + 12];
        float ssq = v0.x*v0.x + v0.y*v0.y + v0.z*v0.z + v0.w*v0.w
                  + v1.x*v1.x + v1.y*v1.y + v1.z*v1.z + v1.w*v1.w
                  + v2.x*v2.x + v2.y*v2.y + v2.z*v2.z + v2.w*v2.w
                  + v3.x*v3.x + v3.y*v3.y + v3.z*v3.z + v3.w*v3.w;
        ssq += __shfl_xor(ssq, 1);
        ssq += __shfl_xor(ssq, 2);
        const float scale = 8.0f / sqrtf(ssq);
        short8 g0, g1;
#pragma unroll
        for (int k = 0; k < 4; ++k) {
            const float a0 = v0[k] * scale, a1 = v1[k] * scale;
            const float a2 = v2[k] * scale, a3 = v3[k] * scale;
            g0[k]     = (short)f2bf(0.5f * a0 * (1.0f + erff(a0 * 0.70710678118654752f)));
            g0[4 + k] = (short)f2bf(0.5f * a1 * (1.0f + erff(a1 * 0.70710678118654752f)));
            g1[k]     = (short)f2bf(0.5f * a2 * (1.0f + erff(a2 * 0.70710678118654752f)));
            g1[4 + k] = (short)f2bf(0.5f * a3 * (1.0f + erff(a3 * 0.70710678118654752f)));
        }
        // coalesced: 4 threads cover one row's 128 B contiguous
        unsigned short* sprow = sp + (size_t)(R0 + r) * 64 + tq * 16;
        *(short8*)(sprow)     = g0;
        *(short8*)(sprow + 8) = g1;
    }
}

// ---------------------------------------------------------------------------
// GEMM2: y[32768][1024] = s'(bf16) @ Pv, swapped MFMA (D[m=d][n=q]),
// float4 stores. grid 2048 x 256 (4 waves); block = 16 q-rows; wave = 256 d-cols.
// High occupancy (2 KB LDS, 8 blocks/CU) -> deep TLP on the store stream.
// First-half PvT frags preloaded BEFORE the staging barrier.
// ---------------------------------------------------------------------------
__global__ __launch_bounds__(256) void gemm2_kernel(
        const unsigned short* __restrict__ sp, const unsigned short* __restrict__ PvT,
        float* __restrict__ out) {
    __shared__ __align__(16) unsigned char sS[16 * 128];  // s' [16][64] bf16 swizzled

    const int tid = threadIdx.x;
    const int w   = tid >> 6;
    const int l   = tid & 63;
    const int lhi = l >> 4;
    const int llo = l & 15;
    const int R0  = blockIdx.x * 16;
    const int N0w = w * 256;

    // stage s' tile (2KB) coalesced, swizzled
    if (tid < 128) {
        const int o = tid * 16;             // flat byte in [16][128]
        const int q = o >> 7;
        ushort8v v = *(const ushort8v*)(sp + (size_t)R0 * 64 + tid * 8);
        *(ushort8v*)(sS + (o ^ ((q & 7) << 4))) = v;
    }

    // preload first-half PvT frags while s' staging is in flight
    short8 pa0[8], pa1[8];
#pragma unroll
    for (int dt = 0; dt < 8; ++dt) {
        const unsigned short* ap = PvT + (size_t)(N0w + dt * 16 + llo) * 64 + lhi * 8;
        pa0[dt] = *(const short8*)ap;
        pa1[dt] = *(const short8*)(ap + 32);
    }
    __syncthreads();

    short8 sb0 = *(const short8*)(sS + ((llo * 128 + lhi * 16)      ^ ((llo & 7) << 4)));
    short8 sb1 = *(const short8*)(sS + ((llo * 128 + 64 + lhi * 16) ^ ((llo & 7) << 4)));

    float* orow = out + (size_t)(R0 + llo) * DD + N0w + lhi * 4;
#pragma unroll
    for (int dt = 0; dt < 8; ++dt) {
        f32x4 acc2 = (f32x4){0.f, 0.f, 0.f, 0.f};
        acc2 = __builtin_amdgcn_mfma_f32_16x16x32_bf16(pa0[dt], sb0, acc2, 0, 0, 0);
        acc2 = __builtin_amdgcn_mfma_f32_16x16x32_bf16(pa1[dt], sb1, acc2, 0, 0, 0);
        *(float4v*)(orow + dt * 16) = acc2;
    }
#pragma unroll
    for (int dt = 8; dt < 16; ++dt) {
        const unsigned short* ap = PvT + (size_t)(N0w + dt * 16 + llo) * 64 + lhi * 8;
        short8 b0 = *(const short8*)ap;
        short8 b1 = *(const short8*)(ap + 32);
        f32x4 acc2 = (f32x4){0.f, 0.f, 0.f, 0.f};
        acc2 = __builtin_amdgcn_mfma_f32_16x16x32_bf16(b0, sb0, acc2, 0, 0, 0);
        acc2 = __builtin_amdgcn_mfma_f32_16x16x32_bf16(b1, sb1, acc2, 0, 0, 0);
        *(float4v*)(orow + dt * 16) = acc2;
    }
}

// ---------------------------------------------------------------------------
extern "C" void kernel_launch(void* const* d_in, const int* in_sizes, int n_in,
                              void* d_out, int out_size, void* d_ws, size_t ws_size,
                              hipStream_t stream) {
    (void)in_sizes; (void)n_in; (void)out_size; (void)ws_size;
    const float* x  = (const float*)d_in[0];
    const float* Wq = (const float*)d_in[1];
    const float* Pk = (const float*)d_in[2];
    const float* Pv = (const float*)d_in[3];
    float* out = (float*)d_out;

    // ws layout (6.25 MB total):
    //   WqT bf16 [1024][1024] @ 0            (2 MB)
    //   Kp  bf16 [64][1024]   @ 2 MB         (128 KB)
    //   PvT bf16 [1024][64]   @ 2 MB + 128K  (128 KB)
    //   s'  bf16 [32768][64]  @ 2.25 MB      (4 MB)
    unsigned short* WqT = (unsigned short*)d_ws;
    unsigned short* Kp  = (unsigned short*)((char*)d_ws + 2097152);
    unsigned short* PvT = (unsigned short*)((char*)d_ws + 2097152 + 131072);
    unsigned short* sp  = (unsigned short*)((char*)d_ws + 2097152 + 262144);

    prep_transpose_kernel<<<272, 256, 0, stream>>>(Wq, Pv, WqT, PvT);
    kp_mfma_kernel<<<64, 256, 0, stream>>>(Pk, WqT, Kp);
    gemm1_kernel<<<256, 512, 0, stream>>>(x, Kp, sp);
    gemm2_kernel<<<2048, 256, 0, stream>>>(sp, PvT, out);
}